// Round 2
// baseline (314.392 us; speedup 1.0000x reference)
//
#include <hip/hip_runtime.h>

#define CS   224
#define HH   1024
#define WW   1024
#define TILE 16
#define NT   14          // 224/16 output tiles per dim
#define LDS_DIM    75    // max input rows/cols per 16-output tile: ceil(16*1024/224)+1 bound
#define LDS_STRIDE 77    // odd stride -> no systematic bank conflicts

// Block: one (n, ch) and a 16x16 output tile. Stage input region in LDS, then
// each thread = one output pixel, sums its window from LDS. Bounds use the
// reference's exact floor/ceil integer divisions.
__global__ __launch_bounds__(256) void cutouts_tiled(
    const float* __restrict__ x,
    const int*   __restrict__ sizesv,
    const int*   __restrict__ oyv,
    const int*   __restrict__ oxv,
    float*       __restrict__ out)
{
    __shared__ float lds[LDS_DIM * LDS_STRIDE];

    int bid  = blockIdx.x;
    int tile = bid % (NT * NT);
    int ch   = (bid / (NT * NT)) % 3;
    int n    = bid / (NT * NT * 3);
    int ti   = tile / NT;
    int tj   = tile % NT;
    int i0   = ti * TILE;
    int j0   = tj * TILE;

    int s  = sizesv[n];
    int oy = oyv[n];
    int ox = oxv[n];

    // Input region covered by this output tile (global image coords):
    int baseR = (i0 * s) / CS;
    int endR  = ((i0 + TILE) * s + CS - 1) / CS;
    int baseC = (j0 * s) / CS;
    int endC  = ((j0 + TILE) * s + CS - 1) / CS;
    int nR = endR - baseR;   // <= 75
    int nC = endC - baseC;   // <= 75

    const float* xc = x + (size_t)ch * (HH * WW)
                        + (size_t)(oy + baseR) * WW + (ox + baseC);

    // Cooperative coalesced staging: 4 row-groups x 64 contiguous columns.
    int tid = threadIdx.x;
    int ty  = tid >> 6;      // 0..3
    int tx  = tid & 63;      // 0..63
    for (int r = ty; r < nR; r += 4) {
        const float* row = xc + (size_t)r * WW;
        for (int c = tx; c < nC; c += 64) {
            lds[r * LDS_STRIDE + c] = row[c];
        }
    }
    __syncthreads();

    // One output pixel per thread.
    int il = tid >> 4;       // 0..15
    int jl = tid & 15;       // 0..15
    int i  = i0 + il;
    int j  = j0 + jl;

    int rl0 = (i * s) / CS - baseR;
    int rl1 = ((i + 1) * s + CS - 1) / CS - baseR;
    int cl0 = (j * s) / CS - baseC;
    int cl1 = ((j + 1) * s + CS - 1) / CS - baseC;

    float sum = 0.0f;
    for (int r = rl0; r < rl1; ++r) {
        for (int c = cl0; c < cl1; ++c) {
            sum += lds[r * LDS_STRIDE + c];
        }
    }

    float area = (float)((rl1 - rl0) * (cl1 - cl0));
    out[((size_t)(n * 3 + ch) * CS + i) * CS + j] = sum / area;
}

extern "C" void kernel_launch(void* const* d_in, const int* in_sizes, int n_in,
                              void* d_out, int out_size, void* d_ws, size_t ws_size,
                              hipStream_t stream) {
    const float* x     = (const float*)d_in[0];
    const int*   sizes = (const int*)d_in[1];
    const int*   oy    = (const int*)d_in[2];
    const int*   ox    = (const int*)d_in[3];
    float*       out   = (float*)d_out;

    int blocks = 128 * 3 * NT * NT;   // 75264
    cutouts_tiled<<<blocks, 256, 0, stream>>>(x, sizes, oy, ox, out);
}

// Round 3
// 219.175 us; speedup vs baseline: 1.4344x; 1.4344x over previous
//
#include <hip/hip_runtime.h>

#define CS   224
#define HH   1024
#define WW   1024

// Fully-unrolled K x K masked window sum. Loads are address-clamped (always
// legal) and masked to zero outside the true [nR x nC] region, so all K*K
// loads issue independently and pipeline (no per-iteration vmcnt(0) stalls).
template<int K>
__device__ __forceinline__ float win_sum(const float* __restrict__ xc,
                                         int r0, int nR, int c0, int nC)
{
    float sum = 0.0f;
#pragma unroll
    for (int dr = 0; dr < K; ++dr) {
        int r = r0 + dr;
        r = r < (HH - 1) ? r : (HH - 1);
        const float* row = xc + r * WW;
        bool vr = (dr < nR);
#pragma unroll
        for (int dc = 0; dc < K; ++dc) {
            int c = c0 + dc;
            c = c < (WW - 1) ? c : (WW - 1);
            float v = row[c];
            sum += (vr && (dc < nC)) ? v : 0.0f;
        }
    }
    return sum;
}

__global__ __launch_bounds__(256) void cutouts_direct(
    const float* __restrict__ x,
    const int*   __restrict__ sizesv,
    const int*   __restrict__ oyv,
    const int*   __restrict__ oxv,
    float*       __restrict__ out)
{
    int idx = blockIdx.x * 256 + threadIdx.x;   // grid sized exactly

    int j  = idx % CS;
    int t  = idx / CS;
    int i  = t % CS;
    t     /= CS;
    int ch = t % 3;
    int n  = t / 3;

    int s   = sizesv[n];
    int oy_ = oyv[n];
    int ox_ = oxv[n];

    // exact reference bounds: lo = floor(i*s/224), hi = ceil((i+1)*s/224)
    int lo_i = (i * s) / CS;
    int nR   = ((i + 1) * s + (CS - 1)) / CS - lo_i;
    int lo_j = (j * s) / CS;
    int nC   = ((j + 1) * s + (CS - 1)) / CS - lo_j;

    int r0 = oy_ + lo_i;
    int c0 = ox_ + lo_j;

    const float* xc = x + (size_t)ch * (HH * WW);

    // K = ceil(s/224)+1 is a proven upper bound on region dims; s is
    // block-uniform -> wave-uniform switch, no divergence.
    int kmax = (s + CS - 1) / CS + 1;

    float sum;
    switch (kmax) {
        case 2:  sum = win_sum<2>(xc, r0, nR, c0, nC); break;
        case 3:  sum = win_sum<3>(xc, r0, nR, c0, nC); break;
        case 4:  sum = win_sum<4>(xc, r0, nR, c0, nC); break;
        case 5:  sum = win_sum<5>(xc, r0, nR, c0, nC); break;
        default: sum = win_sum<6>(xc, r0, nR, c0, nC); break;
    }

    float area = (float)(nR * nC);
    out[idx] = sum / area;
}

extern "C" void kernel_launch(void* const* d_in, const int* in_sizes, int n_in,
                              void* d_out, int out_size, void* d_ws, size_t ws_size,
                              hipStream_t stream) {
    const float* x     = (const float*)d_in[0];
    const int*   sizes = (const int*)d_in[1];
    const int*   oy    = (const int*)d_in[2];
    const int*   ox    = (const int*)d_in[3];
    float*       out   = (float*)d_out;

    int total  = out_size;                 // 128*3*224*224 = 19267584 (divisible by 256)
    int blocks = total / 256;
    cutouts_direct<<<blocks, 256, 0, stream>>>(x, sizes, oy, ox, out);
}

// Round 4
// 120.427 us; speedup vs baseline: 2.6106x; 1.8200x over previous
//
#include <hip/hip_runtime.h>

#define CS   224
#define HH   1024
#define WW   1024
#define HW   (HH * WW)

// ---------------- Pass 1: per-row inclusive cumsum into d_ws ----------------
// I[ch][r][c] = sum_{c'=0..c} x[ch][r][c'],   layout identical to x (12 MB).
__global__ __launch_bounds__(256) void row_cumsum(
    const float* __restrict__ x, float* __restrict__ I)
{
    int row = blockIdx.x;                       // 0 .. 3*1024-1
    const float4* src = (const float4*)(x + (size_t)row * WW);
    float4*       dst = (float4*)(I + (size_t)row * WW);

    int t    = threadIdx.x;                     // 0..255, 4 floats each
    int lane = t & 63;
    int w    = t >> 6;

    float4 v = src[t];
    float s0 = v.x, s1 = s0 + v.y, s2 = s1 + v.z, s3 = s2 + v.w;
    float tsum = s3;

    // wave-inclusive scan of per-thread sums
    float sc = tsum;
    #pragma unroll
    for (int d = 1; d < 64; d <<= 1) {
        float o = __shfl_up(sc, d, 64);
        if (lane >= d) sc += o;
    }

    __shared__ float wsum[4];
    if (lane == 63) wsum[w] = sc;
    __syncthreads();
    float woff = 0.0f;
    #pragma unroll
    for (int k = 0; k < 4; ++k) woff += (k < w) ? wsum[k] : 0.0f;

    float ex = woff + sc - tsum;                // block-exclusive prefix
    dst[t] = make_float4(ex + s0, ex + s1, ex + s2, ex + s3);
}

// ---------------- Pass 2: gather via row-SAT, 2 loads per window row --------
// window col-sum over [c0,c1) = I[r][c1-1] - (c0>0 ? I[r][c0-1] : 0)
template<int K>
__device__ __forceinline__ float sat_sum(const float* __restrict__ Ibase,
                                         int r0, int nR, int b, int ac,
                                         bool amask)
{
    float sum = 0.0f;
#pragma unroll
    for (int dr = 0; dr < K; ++dr) {
        int rr = r0 + dr;
        rr = rr < (HH - 1) ? rr : (HH - 1);     // clamp masked taps to legal addr
        const float* Ir = Ibase + (size_t)rr * WW;
        float vb = Ir[b];
        float va = Ir[ac];
        float rowsum = vb - (amask ? va : 0.0f);
        sum += (dr < nR) ? rowsum : 0.0f;
    }
    return sum;
}

__global__ __launch_bounds__(256) void cutouts_sat(
    const float* __restrict__ I,
    const int*   __restrict__ sizesv,
    const int*   __restrict__ oyv,
    const int*   __restrict__ oxv,
    float*       __restrict__ out)
{
    int idx = blockIdx.x * 256 + threadIdx.x;

    int j  = idx % CS;
    int t  = idx / CS;
    int i  = t % CS;
    t     /= CS;
    int ch = t % 3;
    int n  = t / 3;

    int s   = sizesv[n];
    int oy_ = oyv[n];
    int ox_ = oxv[n];

    // exact reference bounds
    int lo_i = (i * s) / CS;
    int nR   = ((i + 1) * s + (CS - 1)) / CS - lo_i;
    int lo_j = (j * s) / CS;
    int nC   = ((j + 1) * s + (CS - 1)) / CS - lo_j;

    int r0 = oy_ + lo_i;
    int c0 = ox_ + lo_j;
    int c1 = c0 + nC;                            // = ox_ + hi_j

    int  b     = c1 - 1;                         // >= 0 always
    int  a     = c0 - 1;                         // may be -1
    bool amask = (a >= 0);
    int  ac    = amask ? a : 0;

    const float* Ibase = I + (size_t)ch * HW;

    int kmax = (s + CS - 1) / CS + 1;            // wave-uniform

    float sum;
    switch (kmax) {
        case 2:  sum = sat_sum<2>(Ibase, r0, nR, b, ac, amask); break;
        case 3:  sum = sat_sum<3>(Ibase, r0, nR, b, ac, amask); break;
        case 4:  sum = sat_sum<4>(Ibase, r0, nR, b, ac, amask); break;
        case 5:  sum = sat_sum<5>(Ibase, r0, nR, b, ac, amask); break;
        default: sum = sat_sum<6>(Ibase, r0, nR, b, ac, amask); break;
    }

    float area = (float)(nR * nC);
    out[idx] = sum / area;
}

extern "C" void kernel_launch(void* const* d_in, const int* in_sizes, int n_in,
                              void* d_out, int out_size, void* d_ws, size_t ws_size,
                              hipStream_t stream) {
    const float* x     = (const float*)d_in[0];
    const int*   sizes = (const int*)d_in[1];
    const int*   oy    = (const int*)d_in[2];
    const int*   ox    = (const int*)d_in[3];
    float*       out   = (float*)d_out;
    float*       I     = (float*)d_ws;          // 3*1024*1024*4 = 12 MB

    row_cumsum<<<3 * HH, 256, 0, stream>>>(x, I);

    int total  = out_size;                       // 128*3*224*224
    int blocks = total / 256;
    cutouts_sat<<<blocks, 256, 0, stream>>>(I, sizes, oy, ox, out);
}

// Round 5
// 105.559 us; speedup vs baseline: 2.9784x; 1.1408x over previous
//
#include <hip/hip_runtime.h>

#define CS   224
#define HH   1024
#define WW   1024
#define HW   (HH * WW)
#define RT   64              // rows per column-cumsum tile
#define NTIL (HH / RT)       // 16 tiles
#define NCOLG (WW / 256)     // 4 col groups of 256

// ---------------- Pass 1: per-row inclusive cumsum into I (d_ws) ------------
__global__ __launch_bounds__(256) void row_cumsum(
    const float* __restrict__ x, float* __restrict__ I)
{
    int row = blockIdx.x;                       // 0 .. 3*1024-1
    const float4* src = (const float4*)(x + (size_t)row * WW);
    float4*       dst = (float4*)(I + (size_t)row * WW);

    int t    = threadIdx.x;                     // 0..255, 4 floats each
    int lane = t & 63;
    int w    = t >> 6;

    float4 v = src[t];
    float s0 = v.x, s1 = s0 + v.y, s2 = s1 + v.z, s3 = s2 + v.w;
    float tsum = s3;

    float sc = tsum;
    #pragma unroll
    for (int d = 1; d < 64; d <<= 1) {
        float o = __shfl_up(sc, d, 64);
        if (lane >= d) sc += o;
    }

    __shared__ float wsum[4];
    if (lane == 63) wsum[w] = sc;
    __syncthreads();
    float woff = 0.0f;
    #pragma unroll
    for (int k = 0; k < 4; ++k) woff += (k < w) ? wsum[k] : 0.0f;

    float ex = woff + sc - tsum;
    dst[t] = make_float4(ex + s0, ex + s1, ex + s2, ex + s3);
}

// ------- Pass 2: partial column cumsum per 64-row tile; emit tile sums ------
// grid = 3ch * 4colgroups * 16tiles. S[ch][tile][col] = tile column sum.
__global__ __launch_bounds__(256) void col_partial(
    float* __restrict__ I, float* __restrict__ S)
{
    int b    = blockIdx.x;
    int tile = b % NTIL;
    int cg   = (b / NTIL) % NCOLG;
    int ch   = b / (NTIL * NCOLG);
    int c    = cg * 256 + threadIdx.x;

    float* base = I + (size_t)ch * HW + (size_t)(tile * RT) * WW + c;
    float acc = 0.0f;
    #pragma unroll 4
    for (int r = 0; r < RT; ++r) {
        float v = base[r * WW];
        acc += v;
        base[r * WW] = acc;
    }
    S[((ch * NTIL) + tile) * WW + c] = acc;
}

// ------- Pass 3: add scanned tile offsets (tiles 1..15) ----------------------
__global__ __launch_bounds__(256) void col_fixup(
    float* __restrict__ I, const float* __restrict__ S)
{
    int b    = blockIdx.x;
    int tile = b % (NTIL - 1) + 1;
    int cg   = (b / (NTIL - 1)) % NCOLG;
    int ch   = b / ((NTIL - 1) * NCOLG);
    int c    = cg * 256 + threadIdx.x;

    float off = 0.0f;
    for (int t = 0; t < tile; ++t)
        off += S[((ch * NTIL) + t) * WW + c];

    float* base = I + (size_t)ch * HW + (size_t)(tile * RT) * WW + c;
    #pragma unroll 4
    for (int r = 0; r < RT; ++r)
        base[r * WW] += off;
}

// ------- Pass 4: gather — 4 masked SAT taps per output pixel ----------------
__global__ __launch_bounds__(256) void cutouts_sat2d(
    const float* __restrict__ I,
    const int*   __restrict__ sizesv,
    const int*   __restrict__ oyv,
    const int*   __restrict__ oxv,
    float*       __restrict__ out)
{
    int idx = blockIdx.x * 256 + threadIdx.x;

    int j  = idx % CS;
    int t  = idx / CS;
    int i  = t % CS;
    t     /= CS;
    int ch = t % 3;
    int n  = t / 3;

    int s   = sizesv[n];
    int oy_ = oyv[n];
    int ox_ = oxv[n];

    // exact reference bounds
    int lo_i = (i * s) / CS;
    int nR   = ((i + 1) * s + (CS - 1)) / CS - lo_i;
    int lo_j = (j * s) / CS;
    int nC   = ((j + 1) * s + (CS - 1)) / CS - lo_j;

    int r0 = oy_ + lo_i;               // window rows [r0, r0+nR)
    int c0 = ox_ + lo_j;               // window cols [c0, c0+nC)

    int  r1m   = r0 + nR - 1;          // <= 1023, always valid
    int  bcol  = c0 + nC - 1;          // >= 0,   always valid
    bool rmask = (r0 > 0);
    bool amask = (c0 > 0);
    int  r0m   = rmask ? (r0 - 1) : 0;
    int  acol  = amask ? (c0 - 1) : 0;

    const float* Ibase = I + (size_t)ch * HW;
    const float* Rhi = Ibase + (size_t)r1m * WW;
    const float* Rlo = Ibase + (size_t)r0m * WW;

    float t11 = Rhi[bcol];
    float t10 = Rhi[acol];
    float t01 = Rlo[bcol];
    float t00 = Rlo[acol];

    float sum = t11
              - (amask ? t10 : 0.0f)
              - (rmask ? t01 : 0.0f)
              + ((amask && rmask) ? t00 : 0.0f);

    float area = (float)(nR * nC);
    out[idx] = sum / area;
}

extern "C" void kernel_launch(void* const* d_in, const int* in_sizes, int n_in,
                              void* d_out, int out_size, void* d_ws, size_t ws_size,
                              hipStream_t stream) {
    const float* x     = (const float*)d_in[0];
    const int*   sizes = (const int*)d_in[1];
    const int*   oy    = (const int*)d_in[2];
    const int*   ox    = (const int*)d_in[3];
    float*       out   = (float*)d_out;
    float*       I     = (float*)d_ws;               // 3*1024*1024*4 = 12 MB

    // Tile-sum scratch lives in the tail of d_out (192 KB); the gather pass
    // overwrites ALL of d_out afterwards, so this is safe and deterministic.
    float* S = out + (out_size - 3 * NTIL * WW);     // 49152 floats

    row_cumsum<<<3 * HH, 256, 0, stream>>>(x, I);
    col_partial<<<3 * NCOLG * NTIL, 256, 0, stream>>>(I, S);
    col_fixup<<<3 * NCOLG * (NTIL - 1), 256, 0, stream>>>(I, S);

    int blocks = out_size / 256;                     // 75264
    cutouts_sat2d<<<blocks, 256, 0, stream>>>(I, sizes, oy, ox, out);
}

// Round 6
// 104.579 us; speedup vs baseline: 3.0063x; 1.0094x over previous
//
#include <hip/hip_runtime.h>

#define CS   224
#define HH   1024
#define WW   1024
#define HW   (HH * WW)
#define RT   16              // rows per column-cumsum tile
#define NTIL (HH / RT)       // 64
#define NCOLG 2              // 1024 cols / (256 threads * 2 floats)

// ---------------- Pass 1: per-row inclusive cumsum into I (d_ws) ------------
__global__ __launch_bounds__(256) void row_cumsum(
    const float* __restrict__ x, float* __restrict__ I)
{
    int row = blockIdx.x;                       // 0 .. 3*1024-1
    const float4* src = (const float4*)(x + (size_t)row * WW);
    float4*       dst = (float4*)(I + (size_t)row * WW);

    int t    = threadIdx.x;                     // 0..255, 4 floats each
    int lane = t & 63;
    int w    = t >> 6;

    float4 v = src[t];
    float s0 = v.x, s1 = s0 + v.y, s2 = s1 + v.z, s3 = s2 + v.w;
    float tsum = s3;

    float sc = tsum;
    #pragma unroll
    for (int d = 1; d < 64; d <<= 1) {
        float o = __shfl_up(sc, d, 64);
        if (lane >= d) sc += o;
    }

    __shared__ float wsum[4];
    if (lane == 63) wsum[w] = sc;
    __syncthreads();
    float woff = 0.0f;
    #pragma unroll
    for (int k = 0; k < 4; ++k) woff += (k < w) ? wsum[k] : 0.0f;

    float ex = woff + sc - tsum;
    dst[t] = make_float4(ex + s0, ex + s1, ex + s2, ex + s3);
}

// ------- Pass 2: partial column cumsum per 16-row tile (float2 lanes) -------
__global__ __launch_bounds__(256) void col_partial(
    float* __restrict__ I, float* __restrict__ Sf)
{
    int b    = blockIdx.x;
    int tile = b % NTIL;
    int cg   = (b / NTIL) % NCOLG;
    int ch   = b / (NTIL * NCOLG);
    int c2   = cg * 256 + threadIdx.x;          // float2 column index

    float2* base = (float2*)(I + (size_t)ch * HW + (size_t)(tile * RT) * WW) + c2;
    float2* S2   = (float2*)Sf;

    float2 acc = make_float2(0.0f, 0.0f);
    #pragma unroll
    for (int r = 0; r < RT; ++r) {
        float2 v = base[(size_t)r * (WW / 2)];
        acc.x += v.x; acc.y += v.y;
        base[(size_t)r * (WW / 2)] = acc;
    }
    S2[(size_t)(ch * NTIL + tile) * (WW / 2) + c2] = acc;
}

// ------- Pass 3: add scanned tile offsets (tiles 1..NTIL-1) ------------------
__global__ __launch_bounds__(256) void col_fixup(
    float* __restrict__ I, const float* __restrict__ Sf)
{
    int b    = blockIdx.x;
    int tile = b % (NTIL - 1) + 1;
    int cg   = (b / (NTIL - 1)) % NCOLG;
    int ch   = b / ((NTIL - 1) * NCOLG);
    int c2   = cg * 256 + threadIdx.x;

    const float2* S2 = (const float2*)Sf;
    float2 off = make_float2(0.0f, 0.0f);
    for (int t = 0; t < tile; ++t) {
        float2 v = S2[(size_t)(ch * NTIL + t) * (WW / 2) + c2];
        off.x += v.x; off.y += v.y;
    }

    float2* base = (float2*)(I + (size_t)ch * HW + (size_t)(tile * RT) * WW) + c2;
    #pragma unroll
    for (int r = 0; r < RT; ++r) {
        float2 v = base[(size_t)r * (WW / 2)];
        v.x += off.x; v.y += off.y;
        base[(size_t)r * (WW / 2)] = v;
    }
}

// ------- Pass 4: gather — one wave per output row, 4 cols per lane ----------
// Row-level math is wave-uniform (readfirstlane -> SGPR); per-lane work is
// 2 magic-divs + 4 taps + ~7 FP ops per output. ch is the slowest block dim
// so the in-flight working set is one 4 MB channel plane (fits per-XCD L2).
__global__ __launch_bounds__(256) void cutouts_gather(
    const float* __restrict__ I,
    const int*   __restrict__ sizesv,
    const int*   __restrict__ oyv,
    const int*   __restrict__ oxv,
    float*       __restrict__ out)
{
    int bid = blockIdx.x;
    int rg  = bid % 56;            // row group (4 rows per block)
    int rem = bid / 56;
    int n   = rem % 128;
    int ch  = rem / 128;           // slowest

    int tid  = threadIdx.x;
    int w    = tid >> 6;           // wave in block -> row within group
    int lane = tid & 63;
    if (lane >= 56) return;        // 56 lanes x 4 cols = 224

    int s   = sizesv[n];           // block-uniform -> scalar loads
    int oy_ = oyv[n];
    int ox_ = oxv[n];

    int i    = rg * 4 + w;         // wave-uniform
    int lo_i = (i * s) / CS;
    int nR   = ((i + 1) * s + (CS - 1)) / CS - lo_i;
    int r0   = oy_ + lo_i;

    // force row-level values into SGPRs (wave-uniform by construction)
    int r1m = __builtin_amdgcn_readfirstlane(r0 + nR - 1);
    int r0s = __builtin_amdgcn_readfirstlane(r0);
    int nRs = __builtin_amdgcn_readfirstlane(nR);
    bool rm = (r0s > 0);
    int r0m = rm ? (r0s - 1) : 0;

    const float* Ibase = I + (size_t)ch * HW;
    const float* Rhi   = Ibase + (size_t)r1m * WW;
    const float* Rlo   = Ibase + (size_t)r0m * WW;

    float fnR = (float)nRs;

    int j0 = lane * 4;
    float res[4];
    #pragma unroll
    for (int k = 0; k < 4; ++k) {
        int j  = j0 + k;
        int c0 = ox_ + (j * s) / CS;
        int c1 = ox_ + ((j + 1) * s + (CS - 1)) / CS;   // exclusive
        int bcol = c1 - 1;                              // >= 0 always
        bool am  = (c0 > 0);
        int acol = am ? (c0 - 1) : 0;

        float t11 = Rhi[bcol];
        float t10 = Rhi[acol];
        float t01 = Rlo[bcol];
        float t00 = Rlo[acol];

        float sum = t11
                  - (am ? t10 : 0.0f)
                  - (rm ? t01 : 0.0f)
                  + ((am && rm) ? t00 : 0.0f);

        float area = fnR * (float)(c1 - c0);
        res[k] = sum * __builtin_amdgcn_rcpf(area);
    }

    size_t obase = ((size_t)((n * 3 + ch) * CS + i)) * CS + j0;
    *(float4*)(out + obase) = make_float4(res[0], res[1], res[2], res[3]);
}

extern "C" void kernel_launch(void* const* d_in, const int* in_sizes, int n_in,
                              void* d_out, int out_size, void* d_ws, size_t ws_size,
                              hipStream_t stream) {
    const float* x     = (const float*)d_in[0];
    const int*   sizes = (const int*)d_in[1];
    const int*   oy    = (const int*)d_in[2];
    const int*   ox    = (const int*)d_in[3];
    float*       out   = (float*)d_out;
    float*       I     = (float*)d_ws;               // 12 MB

    // Tile-sum scratch in the tail of d_out (768 KB); fully overwritten by
    // the gather pass afterwards -> safe and deterministic.
    float* S = out + (out_size - 3 * NTIL * WW);

    row_cumsum<<<3 * HH, 256, 0, stream>>>(x, I);
    col_partial<<<3 * NCOLG * NTIL, 256, 0, stream>>>(I, S);
    col_fixup<<<3 * NCOLG * (NTIL - 1), 256, 0, stream>>>(I, S);

    int blocks = 3 * 128 * 56;                        // 21504
    cutouts_gather<<<blocks, 256, 0, stream>>>(I, sizes, oy, ox, out);
}

// Round 7
// 87.694 us; speedup vs baseline: 3.5851x; 1.1925x over previous
//
#include <hip/hip_runtime.h>

#define CS   224
#define HH   1024
#define WW   1024
#define HW   (HH * WW)
#define RT   16              // rows per column tile
#define NTIL (HH / RT)       // 64
#define NCOLG 2              // 1024 cols / (256 threads * 2 floats)

// ---- Pass A: fused row-cumsum + within-tile column accumulation ------------
// Per block: one (ch, 16-row tile). For each row: vectorized cross-lane row
// scan (as before), then acc += rowscan (register column accumulator), write
// partial SAT. Tile column sums go to S for the fixup pass.
__global__ __launch_bounds__(256) void sat_rowcol(
    const float* __restrict__ x, float* __restrict__ I, float* __restrict__ S)
{
    int b    = blockIdx.x;
    int tile = b % NTIL;
    int ch   = b / NTIL;

    int t    = threadIdx.x;
    int lane = t & 63;
    int w    = t >> 6;

    __shared__ float wsum[4];

    const float4* xb = (const float4*)(x + (size_t)ch * HW);
    float4*       Ib = (float4*)(I + (size_t)ch * HW);

    float4 acc = make_float4(0.0f, 0.0f, 0.0f, 0.0f);

    for (int r8 = 0; r8 < RT; ++r8) {
        int row = tile * RT + r8;
        float4 v = xb[(size_t)row * (WW / 4) + t];
        float s0 = v.x, s1 = s0 + v.y, s2 = s1 + v.z, s3 = s2 + v.w;
        float tsum = s3, sc = tsum;
        #pragma unroll
        for (int d = 1; d < 64; d <<= 1) {
            float o = __shfl_up(sc, d, 64);
            if (lane >= d) sc += o;
        }
        if (lane == 63) wsum[w] = sc;
        __syncthreads();
        float woff = 0.0f;
        #pragma unroll
        for (int k = 0; k < 4; ++k) woff += (k < w) ? wsum[k] : 0.0f;
        __syncthreads();                       // wsum reused next iteration
        float ex = woff + sc - tsum;
        acc.x += ex + s0; acc.y += ex + s1; acc.z += ex + s2; acc.w += ex + s3;
        Ib[(size_t)row * (WW / 4) + t] = acc;
    }
    ((float4*)S)[(size_t)(ch * NTIL + tile) * (WW / 4) + t] = acc;
}

// ---- Pass B: add scanned tile offsets (tiles 1..NTIL-1) --------------------
__global__ __launch_bounds__(256) void col_fixup(
    float* __restrict__ I, const float* __restrict__ Sf)
{
    int b    = blockIdx.x;
    int tile = b % (NTIL - 1) + 1;
    int cg   = (b / (NTIL - 1)) % NCOLG;
    int ch   = b / ((NTIL - 1) * NCOLG);
    int c2   = cg * 256 + threadIdx.x;

    const float2* S2 = (const float2*)Sf;
    float2 off = make_float2(0.0f, 0.0f);
    for (int t = 0; t < tile; ++t) {
        float2 v = S2[(size_t)(ch * NTIL + t) * (WW / 2) + c2];
        off.x += v.x; off.y += v.y;
    }

    float2* base = (float2*)(I + (size_t)ch * HW + (size_t)(tile * RT) * WW) + c2;
    #pragma unroll
    for (int r = 0; r < RT; ++r) {
        float2 v = base[(size_t)r * (WW / 2)];
        v.x += off.x; v.y += off.y;
        base[(size_t)r * (WW / 2)] = v;
    }
}

// ---- Pass C: gather. Block = one output row; thread = one column. ----------
// Row math (i,n,ch-dependent) is block-uniform -> SALU + scalar loads.
// Adjacent lanes read adjacent j -> tap stride s/224 floats: minimal L1
// line-transactions per wave-load. 4 masked SAT taps, rcp for the divide.
__global__ __launch_bounds__(256) void cutouts_gather(
    const float* __restrict__ I,
    const int*   __restrict__ sizesv,
    const int*   __restrict__ oyv,
    const int*   __restrict__ oxv,
    float*       __restrict__ out)
{
    int b   = blockIdx.x;              // ((ch*128)+n)*224 + i
    int i   = b % CS;
    int rem = b / CS;
    int n   = rem % 128;
    int ch  = rem / 128;               // slowest: working set = one 4MB plane

    int s   = sizesv[n];
    int oy_ = oyv[n];
    int ox_ = oxv[n];

    int lo_i = (i * s) / CS;
    int nR   = ((i + 1) * s + (CS - 1)) / CS - lo_i;
    int r0   = oy_ + lo_i;
    int r1m  = r0 + nR - 1;
    bool rm  = (r0 > 0);
    int r0m  = rm ? (r0 - 1) : 0;

    const float* Rhi = I + (size_t)ch * HW + (size_t)r1m * WW;
    const float* Rlo = I + (size_t)ch * HW + (size_t)r0m * WW;

    int j  = threadIdx.x;
    int jc = j < (CS - 1) ? j : (CS - 1);      // clamp inactive lanes' math
    int c0 = ox_ + (jc * s) / CS;
    int c1 = ox_ + ((jc + 1) * s + (CS - 1)) / CS;
    int bcol = c1 - 1;                          // >= 0 always
    bool am  = (c0 > 0);
    int acol = am ? (c0 - 1) : 0;

    float t11 = Rhi[bcol];
    float t10 = Rhi[acol];
    float t01 = Rlo[bcol];
    float t00 = Rlo[acol];

    float sum = t11
              - (am ? t10 : 0.0f)
              - (rm ? t01 : 0.0f)
              + ((am && rm) ? t00 : 0.0f);

    float area = (float)nR * (float)(c1 - c0);
    float r    = sum * __builtin_amdgcn_rcpf(area);

    if (j < CS)
        out[((size_t)((n * 3 + ch) * CS) + i) * CS + j] = r;
}

extern "C" void kernel_launch(void* const* d_in, const int* in_sizes, int n_in,
                              void* d_out, int out_size, void* d_ws, size_t ws_size,
                              hipStream_t stream) {
    const float* x     = (const float*)d_in[0];
    const int*   sizes = (const int*)d_in[1];
    const int*   oy    = (const int*)d_in[2];
    const int*   ox    = (const int*)d_in[3];
    float*       out   = (float*)d_out;
    float*       I     = (float*)d_ws;               // 12 MB

    // Tile-sum scratch in the tail of d_out (768 KB); gather overwrites ALL
    // of d_out afterwards -> safe and deterministic.
    float* S = out + (out_size - 3 * NTIL * WW);

    sat_rowcol<<<3 * NTIL, 256, 0, stream>>>(x, I, S);
    col_fixup<<<3 * NCOLG * (NTIL - 1), 256, 0, stream>>>(I, S);

    int blocks = 3 * 128 * CS;                       // 86016
    cutouts_gather<<<blocks, 256, 0, stream>>>(I, sizes, oy, ox, out);
}